// Round 12
// baseline (960.320 us; speedup 1.0000x reference)
//
#include <hip/hip_runtime.h>
#include <cstdint>
#include <cstddef>

#define NB 16
#define NC 64
#define HW 4096
#define SLICE ((size_t)(NB*NC*HW))   // 4194304 floats per state
#define NSTEP 16

// ws layout (float offsets)
#define WS_WT    ((size_t)0)          // wT  [16][3][64 o][64 c] = 196608
#define WS_BV    ((size_t)196608)     // bvec[16][64]            = 1024
#define WS_STATS ((size_t)197632)     // 3 bufs x [16][192][2]   = 3*6144
#define WS_PLA   ((size_t)216064)     // planes A: 4194304 floats (16 MB)
#define WS_PLB   ((size_t)4410368)    // planes B: 4194304 floats

typedef _Float16 half8 __attribute__((ext_vector_type(8)));  // 8 f16 (4 VGPRs)
typedef float f32x4 __attribute__((ext_vector_type(4)));     // MFMA acc

// wT[b][g][o][c] = (lat @ Wk + bk) at j = o*192 + (g*64+c) ; bvec = lat @ Wb + bb
__global__ __launch_bounds__(256) void k_w(const float* __restrict__ lat,
    const float* __restrict__ Wk, const float* __restrict__ bk,
    const float* __restrict__ Wb, const float* __restrict__ bb,
    float* __restrict__ wT, float* __restrict__ bvec) {
  int t = threadIdx.x;
  if (blockIdx.x < 48) {
    int j = blockIdx.x*256 + t;
    float acc[16];
#pragma unroll
    for (int b = 0; b < 16; b++) acc[b] = 0.f;
#pragma unroll 4
    for (int k = 0; k < 512; k++) {
      float wv = Wk[(size_t)k*12288 + j];
#pragma unroll
      for (int b = 0; b < 16; b++) acc[b] = fmaf(lat[b*512 + k], wv, acc[b]);
    }
    int o = j / 192, cf = j % 192;
    int g = cf >> 6, c = cf & 63;
    float bkj = bk[j];
#pragma unroll
    for (int b = 0; b < 16; b++)
      wT[(((size_t)(b*3 + g))*64 + o)*64 + c] = acc[b] + bkj;
  } else if (t < 64) {
    int j = t;
    float acc[16];
#pragma unroll
    for (int b = 0; b < 16; b++) acc[b] = 0.f;
    for (int k = 0; k < 512; k++) {
      float wv = Wb[k*64 + j];
#pragma unroll
      for (int b = 0; b < 16; b++) acc[b] = fmaf(lat[b*512 + k], wv, acc[b]);
    }
    float bbj = bb[j];
#pragma unroll
    for (int b = 0; b < 16; b++) bvec[b*64 + j] = acc[b] + bbj;
  }
}

// embs slice 0 + initial packed planes (delta) + analytic step-0 stats + zero sb1
__global__ void k_init(float* __restrict__ e0, float* __restrict__ plA,
                       float* __restrict__ sb0, float* __restrict__ sb1) {
  int t = threadIdx.x;
  if (blockIdx.x == 0) {
    for (int i = t; i < 6144; i += 256) {
      int rem = i % 384;
      int gc = rem >> 1, e = rem & 1;
      float v = 0.f;
      if (gc == 0) v = 1.0f;                               // sum v = sum v^2 = 1
      else if ((gc == 64 || gc == 128) && e == 1) v = 0.1875f;  // sum g^2 = 12/64
      sb0[i] = v;
      sb1[i] = 0.f;
    }
  }
  int f4 = blockIdx.x*256 + t;
  float4 v = make_float4(0.f, 0.f, 0.f, 0.f);
  if (f4 < 1048576) {
    if ((f4 & 65535) == 520) v.x = 1.0f;            // float idx b*262144+2080
    *(float4*)(e0 + (size_t)f4*4) = v;
  } else {
    int g4 = f4 - 1048576;
    if ((g4 & 65535) == 2080)                        // half idx b*524288+16640
      v.x = __uint_as_float(0x00003C00u);            // half pair (1.0h, 0)
    *(float4*)(plA + (size_t)g4*4) = v;
  }
}

struct SG2 {
  alignas(16) _Float16 Bwin[16*384*8];   // [p 16][wpx 384][cj 8] = 96 KB
  float svL[192], svmuL[192], biasL[64];
};  // ~97.8 KB -> 1 block/CU

// One fused step: sv from raw sums -> W frags (regs) -> 6-row plane window (LDS)
// -> GEMM rows r0-1..r0+2 (2 owned + 2 halo) -> sobel epilogue -> residual write
// + plane pack (owned) + stats of new state via atomics (next step's raw sums).
__global__ __launch_bounds__(256, 1) void k_step(const float* __restrict__ st,
    float* __restrict__ stn, const float* __restrict__ wT,
    const float* __restrict__ bvec, const float* __restrict__ statsR,
    float* __restrict__ statsW, float* __restrict__ statsZ,
    const _Float16* __restrict__ plR, _Float16* __restrict__ plW,
    const float* __restrict__ leakp,
    float* __restrict__ out0, float* __restrict__ out2, int last) {
  __shared__ SG2 sh;
  int bid = blockIdx.x, t = threadIdx.x;
  int b = bid >> 5;
  int r0 = ((((bid & 7) << 2) | ((bid >> 3) & 3))) << 1;   // XCD row banding
  int lane = t & 63, wt = t >> 6, c4 = lane >> 4;
  float leak = fminf(fmaxf(leakp[0], 0.001f), 1000.f);

  // zero the t+2 stats buffer (rotation)
  if (t < 12) statsZ[bid*12 + t] = 0.f;

  // ---- stage 6-row B window (rows r0-2..r0+3, clamp/zero) ----
  const _Float16* plb = plR + (size_t)b*524288;
#pragma unroll
  for (int i = 0; i < 24; i++) {
    int u = t + i*256;
    int p = u / 384, wpx = u % 384;
    int pxg = (r0 - 2)*64 + wpx;
    int pxc = pxg < 0 ? 0 : (pxg > 4095 ? 4095 : pxg);
    float4 v = *(const float4*)(plb + ((size_t)p*4096 + pxc)*8);
    if (pxg < 0 || pxg > 4095) v = make_float4(0.f,0.f,0.f,0.f);
    *(float4*)(sh.Bwin + ((size_t)p*384 + wpx)*8) = v;
  }

  // ---- sv/svmu from raw sums ----
  if (t < 192) {
    float s = statsR[(b*192 + t)*2];
    float q = statsR[(b*192 + t)*2 + 1];
    float mu = s * (1.f/HW);
    float var = fmaxf(q*(1.f/HW) - mu*mu, 0.f);
    float sv = 1.f / sqrtf(var + 1e-5f);
    sh.svL[t] = sv; sh.svmuL[t] = sv * mu;
  }
  __syncthreads();   // svL + Bwin ready

  // ---- W fragments (scaled, hi/lo) in registers + bias ----
  int oa = wt*16 + (lane & 15);
  half8 whi[3][2], wlo[3][2];
  float biasacc = 0.f;
#pragma unroll
  for (int g = 0; g < 3; g++) {
#pragma unroll
    for (int kc = 0; kc < 2; kc++) {
      const float* wrow = wT + (((size_t)(b*3 + g))*64 + oa)*64 + kc*32 + c4*8;
      float4 wa = *(const float4*)wrow;  float4 wb2 = *(const float4*)(wrow + 4);
      float wv[8] = {wa.x,wa.y,wa.z,wa.w, wb2.x,wb2.y,wb2.z,wb2.w};
      half8 hv, lv;
#pragma unroll
      for (int jj = 0; jj < 8; jj++) {
        int cg = g*64 + kc*32 + c4*8 + jj;
        float scaled = wv[jj] * sh.svL[cg];
        biasacc = fmaf(wv[jj], sh.svmuL[cg], biasacc);
        _Float16 h = (_Float16)scaled;
        hv[jj] = h;
        lv[jj] = (_Float16)(scaled - (float)h);
      }
      whi[g][kc] = hv; wlo[g][kc] = lv;
    }
  }
  biasacc += __shfl_xor(biasacc, 16);
  biasacc += __shfl_xor(biasacc, 32);
  if (c4 == 0) sh.biasL[oa] = bvec[b*64 + oa] - biasacc;
  __syncthreads();   // biasL ready

  float nv4[4][16];

#pragma unroll
  for (int rr = 0; rr < 4; rr++) {
    int r = r0 - 1 + rr;
    if (r >= 0 && r < 64) {          // block-uniform
      f32x4 accA[4] = {}; f32x4 accB[12] = {}; f32x4 accC[12] = {};
#pragma unroll
      for (int kc = 0; kc < 2; kc++) {
#pragma unroll
        for (int n = 0; n < 12; n++) {
          int pxl = rr*64 + n*16 + (lane & 15);
          half8 bh = *(const half8*)(sh.Bwin + ((size_t)((     kc*4 + c4)*384) + pxl)*8);
          half8 bl = *(const half8*)(sh.Bwin + ((size_t)((8 +  kc*4 + c4)*384) + pxl)*8);
          accB[n] = __builtin_amdgcn_mfma_f32_16x16x32_f16(whi[1][kc], bh, accB[n], 0,0,0);
          accB[n] = __builtin_amdgcn_mfma_f32_16x16x32_f16(whi[1][kc], bl, accB[n], 0,0,0);
          accB[n] = __builtin_amdgcn_mfma_f32_16x16x32_f16(wlo[1][kc], bh, accB[n], 0,0,0);
          accC[n] = __builtin_amdgcn_mfma_f32_16x16x32_f16(whi[2][kc], bh, accC[n], 0,0,0);
          accC[n] = __builtin_amdgcn_mfma_f32_16x16x32_f16(whi[2][kc], bl, accC[n], 0,0,0);
          accC[n] = __builtin_amdgcn_mfma_f32_16x16x32_f16(wlo[2][kc], bh, accC[n], 0,0,0);
          if (n >= 4 && n < 8) {
            accA[n-4] = __builtin_amdgcn_mfma_f32_16x16x32_f16(whi[0][kc], bh, accA[n-4], 0,0,0);
            accA[n-4] = __builtin_amdgcn_mfma_f32_16x16x32_f16(whi[0][kc], bl, accA[n-4], 0,0,0);
            accA[n-4] = __builtin_amdgcn_mfma_f32_16x16x32_f16(wlo[0][kc], bh, accA[n-4], 0,0,0);
          }
        }
      }

      // epilogue: in-register sobel on mixed images + bias + residual
#pragma unroll
      for (int j = 0; j < 4; j++) {
        int o = wt*16 + (c4 << 2) + j;
        float Sx[4], Sy[4];
#pragma unroll
        for (int nc = 0; nc < 4; nc++) {
          Sx[nc] = accB[nc][j] + 2.f*accB[4+nc][j] + accB[8+nc][j];
          Sy[nc] = accC[8+nc][j] - accC[nc][j];
        }
        float bt = sh.biasL[o];
#pragma unroll
        for (int nc = 0; nc < 4; nc++) {
          int nm = (nc > 0) ? nc-1 : 0;
          int np = (nc < 3) ? nc+1 : 3;
          float xl1 = __shfl(Sx[nc], (lane - 1) & 63);
          float xl2 = (nc > 0) ? __shfl(Sx[nm], (lane + 15) & 63) : 0.f;
          float xL  = (lane & 15) ? xl1 : xl2;
          float xr1 = __shfl(Sx[nc], (lane + 1) & 63);
          float xr2 = (nc < 3) ? __shfl(Sx[np], (lane - 15) & 63) : 0.f;
          float xR  = ((lane & 15) == 15) ? xr2 : xr1;
          float yl1 = __shfl(Sy[nc], (lane - 1) & 63);
          float yl2 = (nc > 0) ? __shfl(Sy[nm], (lane + 15) & 63) : 0.f;
          float yL  = (lane & 15) ? yl1 : yl2;
          float yr1 = __shfl(Sy[nc], (lane + 1) & 63);
          float yr2 = (nc < 3) ? __shfl(Sy[np], (lane - 15) & 63) : 0.f;
          float yR  = ((lane & 15) == 15) ? yr2 : yr1;
          float gx = (xR - xL) * 0.125f;
          float gy = (yL + 2.f*Sy[nc] + yR) * 0.125f;
          float nw = accA[nc][j] + gx + gy + bt;
          int wpx = nc*16 + (lane & 15);
          size_t gi = (size_t)(b*NC + o)*HW + (size_t)r*64 + wpx;
          float nvv = st[gi] + leak * nw;
          nv4[rr][j*4 + nc] = nvv;
          if (rr == 1 || rr == 2) {
            stn[gi] = nvv;
            if (last && o < 3) {
              size_t oi = (size_t)(b*3 + o)*HW + (size_t)r*64 + wpx;
              out2[oi] = nvv;
              out0[oi] = fminf(fmaxf(nvv, -1.f), 1.f);
            }
          }
        }
      }
    } else {
#pragma unroll
      for (int u = 0; u < 16; u++) nv4[rr][u] = 0.f;
    }
  }

  if (!last) {
    // ---- pack owned rows into next-step planes ----
#pragma unroll
    for (int rr = 1; rr <= 2; rr++) {
      int r = r0 - 1 + rr;
      int pl = c4 & 1;
      int g8 = wt*2 + (c4 >> 1);
      _Float16* pw = plW + (size_t)b*524288 + ((size_t)pl*8 + g8)*32768;
#pragma unroll
      for (int nc = 0; nc < 4; nc++) {
        float own[4], rcv[4];
#pragma unroll
        for (int j = 0; j < 4; j++) {
          own[j] = nv4[rr][j*4 + nc];
          rcv[j] = __shfl_xor(own[j], 16);
        }
        float xx[8];
#pragma unroll
        for (int jj = 0; jj < 8; jj++)
          xx[jj] = ((jj >> 2) == (c4 & 1)) ? own[jj & 3] : rcv[jj & 3];
        half8 v8;
        if (pl == 0) {
#pragma unroll
          for (int jj = 0; jj < 8; jj++) v8[jj] = (_Float16)xx[jj];
        } else {
#pragma unroll
          for (int jj = 0; jj < 8; jj++) {
            _Float16 h = (_Float16)xx[jj];
            v8[jj] = (_Float16)(xx[jj] - (float)h);
          }
        }
        int gpx = r*64 + nc*16 + (lane & 15);
        *(half8*)(pw + (size_t)gpx*8) = v8;
      }
    }

    // ---- stats of NEW state (owned rows) -> atomics into statsW ----
#pragma unroll
    for (int j = 0; j < 4; j++) {
      float dxv[4][4], sxv[4][4];
#pragma unroll
      for (int rw = 0; rw < 4; rw++) {
        float vv[4];
#pragma unroll
        for (int nc = 0; nc < 4; nc++) vv[nc] = nv4[rw][j*4 + nc];
#pragma unroll
        for (int nc = 0; nc < 4; nc++) {
          int nm = (nc > 0) ? nc-1 : 0;
          int np = (nc < 3) ? nc+1 : 3;
          float xl1 = __shfl(vv[nc], (lane - 1) & 63);
          float xl2 = (nc > 0) ? __shfl(vv[nm], (lane + 15) & 63) : 0.f;
          float xL  = (lane & 15) ? xl1 : xl2;
          float xr1 = __shfl(vv[nc], (lane + 1) & 63);
          float xr2 = (nc < 3) ? __shfl(vv[np], (lane - 15) & 63) : 0.f;
          float xR  = ((lane & 15) == 15) ? xr2 : xr1;
          dxv[rw][nc] = xR - xL;
          sxv[rw][nc] = xL + 2.f*vv[nc] + xR;
        }
      }
      float s0=0,q0=0,s1=0,q1=0,s2=0,q2=0;
#pragma unroll
      for (int rr = 1; rr <= 2; rr++) {
#pragma unroll
        for (int nc = 0; nc < 4; nc++) {
          float v = nv4[rr][j*4 + nc];
          s0 += v; q0 = fmaf(v, v, q0);
          float gx = (dxv[rr-1][nc] + 2.f*dxv[rr][nc] + dxv[rr+1][nc]) * 0.125f;
          float gy = (sxv[rr+1][nc] - sxv[rr-1][nc]) * 0.125f;
          s1 += gx; q1 = fmaf(gx, gx, q1);
          s2 += gy; q2 = fmaf(gy, gy, q2);
        }
      }
#pragma unroll
      for (int m = 1; m <= 8; m <<= 1) {
        s0 += __shfl_xor(s0, m); q0 += __shfl_xor(q0, m);
        s1 += __shfl_xor(s1, m); q1 += __shfl_xor(q1, m);
        s2 += __shfl_xor(s2, m); q2 += __shfl_xor(q2, m);
      }
      if ((lane & 15) == 0) {
        int o = wt*16 + (c4 << 2) + j;
        atomicAdd(&statsW[((size_t)b*192 +       o)*2    ], s0);
        atomicAdd(&statsW[((size_t)b*192 +       o)*2 + 1], q0);
        atomicAdd(&statsW[((size_t)b*192 +  64 + o)*2    ], s1);
        atomicAdd(&statsW[((size_t)b*192 +  64 + o)*2 + 1], q1);
        atomicAdd(&statsW[((size_t)b*192 + 128 + o)*2    ], s2);
        atomicAdd(&statsW[((size_t)b*192 + 128 + o)*2 + 1], q2);
      }
    }
  }
}

extern "C" void kernel_launch(void* const* d_in, const int* in_sizes, int n_in,
                              void* d_out, int out_size, void* d_ws, size_t ws_size,
                              hipStream_t stream) {
  const float* lat   = (const float*)d_in[0];
  const float* Wk    = (const float*)d_in[1];
  const float* bk    = (const float*)d_in[2];
  const float* Wb    = (const float*)d_in[3];
  const float* bb    = (const float*)d_in[4];
  const float* leakp = (const float*)d_in[5];
  float* out = (float*)d_out;
  float* ws  = (float*)d_ws;
  float* wT    = ws + WS_WT;
  float* bvec  = ws + WS_BV;
  float* sbuf[3] = { ws + WS_STATS, ws + WS_STATS + 6144, ws + WS_STATS + 12288 };
  _Float16* plbuf[2] = { (_Float16*)(ws + WS_PLA), (_Float16*)(ws + WS_PLB) };
  float* out0 = out;
  float* embs = out + 196608;
  float* out2 = out + 196608 + 17*SLICE;

  hipLaunchKernelGGL(k_w,    dim3(49),   dim3(256), 0, stream, lat, Wk, bk, Wb, bb, wT, bvec);
  hipLaunchKernelGGL(k_init, dim3(8192), dim3(256), 0, stream, embs, ws + WS_PLA,
                     sbuf[0], sbuf[1]);
  for (int tstep = 0; tstep < NSTEP; tstep++) {
    const float* stc = embs + (size_t)tstep*SLICE;
    float*       stn = embs + (size_t)(tstep+1)*SLICE;
    hipLaunchKernelGGL(k_step, dim3(512), dim3(256), 0, stream,
                       stc, stn, wT, bvec,
                       sbuf[tstep % 3], sbuf[(tstep+1) % 3], sbuf[(tstep+2) % 3],
                       plbuf[tstep & 1], plbuf[(tstep+1) & 1], leakp,
                       out0, out2, (int)(tstep == NSTEP-1));
  }
}

// Round 13
// 731.566 us; speedup vs baseline: 1.3127x; 1.3127x over previous
//
#include <hip/hip_runtime.h>
#include <cstdint>
#include <cstddef>

#define NB 16
#define NC 64
#define HW 4096
#define SLICE ((size_t)(NB*NC*HW))   // 4194304 floats per state
#define NSTEP 16

// ws layout (float offsets)
#define WS_WT    ((size_t)0)          // wT  [16][3][64 o][64 c] = 196608
#define WS_BV    ((size_t)196608)     // bvec[16][64]            = 1024
#define WS_STATS ((size_t)197632)     // 3 bufs x [16][192][2]   = 3*6144
#define WS_PLA   ((size_t)216064)     // planes A: 4194304 floats (16 MB)
#define WS_PLB   ((size_t)4410368)    // planes B: 4194304 floats

typedef _Float16 half8 __attribute__((ext_vector_type(8)));  // 8 f16 (4 VGPRs)
typedef float f32x4 __attribute__((ext_vector_type(4)));     // MFMA acc

// wT[b][g][o][c] = (lat @ Wk + bk) at j = o*192 + (g*64+c) ; bvec = lat @ Wb + bb
__global__ __launch_bounds__(256) void k_w(const float* __restrict__ lat,
    const float* __restrict__ Wk, const float* __restrict__ bk,
    const float* __restrict__ Wb, const float* __restrict__ bb,
    float* __restrict__ wT, float* __restrict__ bvec) {
  int t = threadIdx.x;
  if (blockIdx.x < 48) {
    int j = blockIdx.x*256 + t;
    float acc[16];
#pragma unroll
    for (int b = 0; b < 16; b++) acc[b] = 0.f;
#pragma unroll 4
    for (int k = 0; k < 512; k++) {
      float wv = Wk[(size_t)k*12288 + j];
#pragma unroll
      for (int b = 0; b < 16; b++) acc[b] = fmaf(lat[b*512 + k], wv, acc[b]);
    }
    int o = j / 192, cf = j % 192;
    int g = cf >> 6, c = cf & 63;
    float bkj = bk[j];
#pragma unroll
    for (int b = 0; b < 16; b++)
      wT[(((size_t)(b*3 + g))*64 + o)*64 + c] = acc[b] + bkj;
  } else if (t < 64) {
    int j = t;
    float acc[16];
#pragma unroll
    for (int b = 0; b < 16; b++) acc[b] = 0.f;
    for (int k = 0; k < 512; k++) {
      float wv = Wb[k*64 + j];
#pragma unroll
      for (int b = 0; b < 16; b++) acc[b] = fmaf(lat[b*512 + k], wv, acc[b]);
    }
    float bbj = bb[j];
#pragma unroll
    for (int b = 0; b < 16; b++) bvec[b*64 + j] = acc[b] + bbj;
  }
}

// embs slice 0 + initial packed planes (delta) + analytic step-0 stats + zero sb1
__global__ void k_init(float* __restrict__ e0, float* __restrict__ plA,
                       float* __restrict__ sb0, float* __restrict__ sb1) {
  int t = threadIdx.x;
  if (blockIdx.x == 0) {
    for (int i = t; i < 6144; i += 256) {
      int rem = i % 384;
      int gc = rem >> 1, e = rem & 1;
      float v = 0.f;
      if (gc == 0) v = 1.0f;                               // sum v = sum v^2 = 1
      else if ((gc == 64 || gc == 128) && e == 1) v = 0.1875f;  // sum g^2 = 12/64
      sb0[i] = v;
      sb1[i] = 0.f;
    }
  }
  int f4 = blockIdx.x*256 + t;
  float4 v = make_float4(0.f, 0.f, 0.f, 0.f);
  if (f4 < 1048576) {
    if ((f4 & 65535) == 520) v.x = 1.0f;            // float idx b*262144+2080
    *(float4*)(e0 + (size_t)f4*4) = v;
  } else {
    int g4 = f4 - 1048576;
    if ((g4 & 65535) == 2080)                        // half idx b*524288+16640
      v.x = __uint_as_float(0x00003C00u);            // half pair (1.0h, 0)
    *(float4*)(plA + (size_t)g4*4) = v;
  }
}

struct SG3 {
  alignas(16) _Float16 Bwin[16*512*8];   // [p 16][wpx 8rows*64][cj 8] = 128 KB
  float svL[192], svmuL[192], biasL[64];
};  // ~130 KB -> 1 block/CU (8 waves with 512 thr)

// One fused step: 256 blocks x 512 thr. Block owns 4 rows (r0..r0+3).
// 8 waves = 4 o-groups x 2 row-halves; wave mixes 4 rows (2 owned wave-local).
// GEMM from pre-packed planes, sobel-after-mix, residual write, plane pack,
// stats of new state via atomics (3-buffer rotation).
__global__ __launch_bounds__(512, 2) void k_step(const float* __restrict__ st,
    float* __restrict__ stn, const float* __restrict__ wT,
    const float* __restrict__ bvec, const float* __restrict__ statsR,
    float* __restrict__ statsW, float* __restrict__ statsZ,
    const _Float16* __restrict__ plR, _Float16* __restrict__ plW,
    const float* __restrict__ leakp,
    float* __restrict__ out0, float* __restrict__ out2, int last) {
  __shared__ SG3 sh;
  int bid = blockIdx.x, t = threadIdx.x;
  int b = bid >> 4, B = bid & 15;
  int r0 = (B & 7) * 8 + (B >> 3) * 4;     // XCD-local 4-row band
  int lane = t & 63, wave = t >> 6, c4 = lane >> 4;
  int og = wave & 3, half = wave >> 2;
  float leak = fminf(fmaxf(leakp[0], 0.001f), 1000.f);

  // zero the t+2 stats buffer (rotation): 6144 / 256 blocks = 24 each
  if (t < 24) statsZ[bid*24 + t] = 0.f;

  // ---- stage 8-row plane window (rows r0-2..r0+5, clamp/zero) ----
  const _Float16* plb = plR + (size_t)b*524288;
#pragma unroll
  for (int i = 0; i < 16; i++) {
    int u = t + i*512;
    int p = u >> 9, wpx = u & 511;
    int pxg = (r0 - 2)*64 + wpx;
    int pxc = pxg < 0 ? 0 : (pxg > 4095 ? 4095 : pxg);
    float4 v = *(const float4*)(plb + ((size_t)p*4096 + pxc)*8);
    if (pxg < 0 || pxg > 4095) v = make_float4(0.f,0.f,0.f,0.f);
    *(float4*)(sh.Bwin + ((size_t)p*512 + wpx)*8) = v;
  }

  // ---- sv/svmu from raw sums ----
  if (t < 192) {
    float s = statsR[(b*192 + t)*2];
    float q = statsR[(b*192 + t)*2 + 1];
    float mu = s * (1.f/HW);
    float var = fmaxf(q*(1.f/HW) - mu*mu, 0.f);
    float sv = 1.f / sqrtf(var + 1e-5f);
    sh.svL[t] = sv; sh.svmuL[t] = sv * mu;
  }
  __syncthreads();   // svL + Bwin ready

  // ---- W fragments (scaled, hi/lo) in registers + bias ----
  int oa = og*16 + (lane & 15);
  half8 whi[3][2], wlo[3][2];
  float biasacc = 0.f;
#pragma unroll
  for (int g = 0; g < 3; g++) {
#pragma unroll
    for (int kc = 0; kc < 2; kc++) {
      const float* wrow = wT + (((size_t)(b*3 + g))*64 + oa)*64 + kc*32 + c4*8;
      float4 wa = *(const float4*)wrow;  float4 wb2 = *(const float4*)(wrow + 4);
      float wv[8] = {wa.x,wa.y,wa.z,wa.w, wb2.x,wb2.y,wb2.z,wb2.w};
      half8 hv, lv;
#pragma unroll
      for (int jj = 0; jj < 8; jj++) {
        int cg = g*64 + kc*32 + c4*8 + jj;
        float scaled = wv[jj] * sh.svL[cg];
        biasacc = fmaf(wv[jj], sh.svmuL[cg], biasacc);
        _Float16 h = (_Float16)scaled;
        hv[jj] = h;
        lv[jj] = (_Float16)(scaled - (float)h);
      }
      whi[g][kc] = hv; wlo[g][kc] = lv;
    }
  }
  biasacc += __shfl_xor(biasacc, 16);
  biasacc += __shfl_xor(biasacc, 32);
  if (c4 == 0) sh.biasL[oa] = bvec[b*64 + oa] - biasacc;   // waves w, w+4 same val
  __syncthreads();   // biasL ready

  int rowbase = r0 - 1 + half*2;   // wave's 4 mix rows: rowbase..rowbase+3
  float nv4[4][16];

#pragma unroll
  for (int m = 0; m < 4; m++) {
    int r = rowbase + m;
    if (r >= 0 && r < 64) {          // wave-uniform
      f32x4 accA[4] = {}; f32x4 accB[12] = {}; f32x4 accC[12] = {};
#pragma unroll
      for (int kc = 0; kc < 2; kc++) {
#pragma unroll
        for (int n = 0; n < 12; n++) {
          int pxl = (half*2 + m)*64 + n*16 + (lane & 15);   // plane row r-1 at n=0
          half8 bh = *(const half8*)(sh.Bwin + ((size_t)(     kc*4 + c4)*512 + pxl)*8);
          half8 bl = *(const half8*)(sh.Bwin + ((size_t)(8 +  kc*4 + c4)*512 + pxl)*8);
          accB[n] = __builtin_amdgcn_mfma_f32_16x16x32_f16(whi[1][kc], bh, accB[n], 0,0,0);
          accB[n] = __builtin_amdgcn_mfma_f32_16x16x32_f16(whi[1][kc], bl, accB[n], 0,0,0);
          accB[n] = __builtin_amdgcn_mfma_f32_16x16x32_f16(wlo[1][kc], bh, accB[n], 0,0,0);
          accC[n] = __builtin_amdgcn_mfma_f32_16x16x32_f16(whi[2][kc], bh, accC[n], 0,0,0);
          accC[n] = __builtin_amdgcn_mfma_f32_16x16x32_f16(whi[2][kc], bl, accC[n], 0,0,0);
          accC[n] = __builtin_amdgcn_mfma_f32_16x16x32_f16(wlo[2][kc], bh, accC[n], 0,0,0);
          if (n >= 4 && n < 8) {
            accA[n-4] = __builtin_amdgcn_mfma_f32_16x16x32_f16(whi[0][kc], bh, accA[n-4], 0,0,0);
            accA[n-4] = __builtin_amdgcn_mfma_f32_16x16x32_f16(whi[0][kc], bl, accA[n-4], 0,0,0);
            accA[n-4] = __builtin_amdgcn_mfma_f32_16x16x32_f16(wlo[0][kc], bh, accA[n-4], 0,0,0);
          }
        }
      }

      // epilogue: in-register sobel on mixed images + bias + residual
#pragma unroll
      for (int j = 0; j < 4; j++) {
        int o = og*16 + (c4 << 2) + j;
        float Sx[4], Sy[4];
#pragma unroll
        for (int nc = 0; nc < 4; nc++) {
          Sx[nc] = accB[nc][j] + 2.f*accB[4+nc][j] + accB[8+nc][j];
          Sy[nc] = accC[8+nc][j] - accC[nc][j];
        }
        float bt = sh.biasL[o];
#pragma unroll
        for (int nc = 0; nc < 4; nc++) {
          int nm = (nc > 0) ? nc-1 : 0;
          int np = (nc < 3) ? nc+1 : 3;
          float xl1 = __shfl(Sx[nc], (lane - 1) & 63);
          float xl2 = (nc > 0) ? __shfl(Sx[nm], (lane + 15) & 63) : 0.f;
          float xL  = (lane & 15) ? xl1 : xl2;
          float xr1 = __shfl(Sx[nc], (lane + 1) & 63);
          float xr2 = (nc < 3) ? __shfl(Sx[np], (lane - 15) & 63) : 0.f;
          float xR  = ((lane & 15) == 15) ? xr2 : xr1;
          float yl1 = __shfl(Sy[nc], (lane - 1) & 63);
          float yl2 = (nc > 0) ? __shfl(Sy[nm], (lane + 15) & 63) : 0.f;
          float yL  = (lane & 15) ? yl1 : yl2;
          float yr1 = __shfl(Sy[nc], (lane + 1) & 63);
          float yr2 = (nc < 3) ? __shfl(Sy[np], (lane - 15) & 63) : 0.f;
          float yR  = ((lane & 15) == 15) ? yr2 : yr1;
          float gx = (xR - xL) * 0.125f;
          float gy = (yL + 2.f*Sy[nc] + yR) * 0.125f;
          float nw = accA[nc][j] + gx + gy + bt;
          int wpx = nc*16 + (lane & 15);
          size_t gi = (size_t)(b*NC + o)*HW + (size_t)r*64 + wpx;
          float nvv = st[gi] + leak * nw;
          nv4[m][j*4 + nc] = nvv;
          if (m == 1 || m == 2) {     // owned rows
            stn[gi] = nvv;
            if (last && o < 3) {
              size_t oi = (size_t)(b*3 + o)*HW + (size_t)r*64 + wpx;
              out2[oi] = nvv;
              out0[oi] = fminf(fmaxf(nvv, -1.f), 1.f);
            }
          }
        }
      }
    } else {
#pragma unroll
      for (int u = 0; u < 16; u++) nv4[m][u] = 0.f;
    }
  }

  if (!last) {
    // ---- pack owned rows into next-step planes ----
#pragma unroll
    for (int m = 1; m <= 2; m++) {
      int r = rowbase + m;
      int pl = c4 & 1;
      int g8 = og*2 + (c4 >> 1);
      _Float16* pw = plW + (size_t)b*524288 + ((size_t)pl*8 + g8)*32768;
#pragma unroll
      for (int nc = 0; nc < 4; nc++) {
        float own[4], rcv[4];
#pragma unroll
        for (int j = 0; j < 4; j++) {
          own[j] = nv4[m][j*4 + nc];
          rcv[j] = __shfl_xor(own[j], 16);
        }
        float xx[8];
#pragma unroll
        for (int jj = 0; jj < 8; jj++)
          xx[jj] = ((jj >> 2) == (c4 & 1)) ? own[jj & 3] : rcv[jj & 3];
        half8 v8;
        if (pl == 0) {
#pragma unroll
          for (int jj = 0; jj < 8; jj++) v8[jj] = (_Float16)xx[jj];
        } else {
#pragma unroll
          for (int jj = 0; jj < 8; jj++) {
            _Float16 h = (_Float16)xx[jj];
            v8[jj] = (_Float16)(xx[jj] - (float)h);
          }
        }
        int gpx = r*64 + nc*16 + (lane & 15);
        *(half8*)(pw + (size_t)gpx*8) = v8;
      }
    }

    // ---- stats of NEW state (owned rows m=1,2; neighbors wave-local) ----
#pragma unroll
    for (int j = 0; j < 4; j++) {
      float dxv[4][4], sxv[4][4];
#pragma unroll
      for (int rw = 0; rw < 4; rw++) {
        float vv[4];
#pragma unroll
        for (int nc = 0; nc < 4; nc++) vv[nc] = nv4[rw][j*4 + nc];
#pragma unroll
        for (int nc = 0; nc < 4; nc++) {
          int nm = (nc > 0) ? nc-1 : 0;
          int np = (nc < 3) ? nc+1 : 3;
          float xl1 = __shfl(vv[nc], (lane - 1) & 63);
          float xl2 = (nc > 0) ? __shfl(vv[nm], (lane + 15) & 63) : 0.f;
          float xL  = (lane & 15) ? xl1 : xl2;
          float xr1 = __shfl(vv[nc], (lane + 1) & 63);
          float xr2 = (nc < 3) ? __shfl(vv[np], (lane - 15) & 63) : 0.f;
          float xR  = ((lane & 15) == 15) ? xr2 : xr1;
          dxv[rw][nc] = xR - xL;
          sxv[rw][nc] = xL + 2.f*vv[nc] + xR;
        }
      }
      float s0=0,q0=0,s1=0,q1=0,s2=0,q2=0;
#pragma unroll
      for (int m = 1; m <= 2; m++) {
#pragma unroll
        for (int nc = 0; nc < 4; nc++) {
          float v = nv4[m][j*4 + nc];
          s0 += v; q0 = fmaf(v, v, q0);
          float gx = (dxv[m-1][nc] + 2.f*dxv[m][nc] + dxv[m+1][nc]) * 0.125f;
          float gy = (sxv[m+1][nc] - sxv[m-1][nc]) * 0.125f;
          s1 += gx; q1 = fmaf(gx, gx, q1);
          s2 += gy; q2 = fmaf(gy, gy, q2);
        }
      }
#pragma unroll
      for (int mm = 1; mm <= 8; mm <<= 1) {
        s0 += __shfl_xor(s0, mm); q0 += __shfl_xor(q0, mm);
        s1 += __shfl_xor(s1, mm); q1 += __shfl_xor(q1, mm);
        s2 += __shfl_xor(s2, mm); q2 += __shfl_xor(q2, mm);
      }
      if ((lane & 15) == 0) {
        int o = og*16 + (c4 << 2) + j;
        atomicAdd(&statsW[((size_t)b*192 +       o)*2    ], s0);
        atomicAdd(&statsW[((size_t)b*192 +       o)*2 + 1], q0);
        atomicAdd(&statsW[((size_t)b*192 +  64 + o)*2    ], s1);
        atomicAdd(&statsW[((size_t)b*192 +  64 + o)*2 + 1], q1);
        atomicAdd(&statsW[((size_t)b*192 + 128 + o)*2    ], s2);
        atomicAdd(&statsW[((size_t)b*192 + 128 + o)*2 + 1], q2);
      }
    }
  }
}

extern "C" void kernel_launch(void* const* d_in, const int* in_sizes, int n_in,
                              void* d_out, int out_size, void* d_ws, size_t ws_size,
                              hipStream_t stream) {
  const float* lat   = (const float*)d_in[0];
  const float* Wk    = (const float*)d_in[1];
  const float* bk    = (const float*)d_in[2];
  const float* Wb    = (const float*)d_in[3];
  const float* bb    = (const float*)d_in[4];
  const float* leakp = (const float*)d_in[5];
  float* out = (float*)d_out;
  float* ws  = (float*)d_ws;
  float* wT    = ws + WS_WT;
  float* bvec  = ws + WS_BV;
  float* sbuf[3] = { ws + WS_STATS, ws + WS_STATS + 6144, ws + WS_STATS + 12288 };
  _Float16* plbuf[2] = { (_Float16*)(ws + WS_PLA), (_Float16*)(ws + WS_PLB) };
  float* out0 = out;
  float* embs = out + 196608;
  float* out2 = out + 196608 + 17*SLICE;

  hipLaunchKernelGGL(k_w,    dim3(49),   dim3(256), 0, stream, lat, Wk, bk, Wb, bb, wT, bvec);
  hipLaunchKernelGGL(k_init, dim3(8192), dim3(256), 0, stream, embs, ws + WS_PLA,
                     sbuf[0], sbuf[1]);
  for (int tstep = 0; tstep < NSTEP; tstep++) {
    const float* stc = embs + (size_t)tstep*SLICE;
    float*       stn = embs + (size_t)(tstep+1)*SLICE;
    hipLaunchKernelGGL(k_step, dim3(256), dim3(512), 0, stream,
                       stc, stn, wT, bvec,
                       sbuf[tstep % 3], sbuf[(tstep+1) % 3], sbuf[(tstep+2) % 3],
                       plbuf[tstep & 1], plbuf[(tstep+1) & 1], leakp,
                       out0, out2, (int)(tstep == NSTEP-1));
  }
}

// Round 14
// 584.800 us; speedup vs baseline: 1.6421x; 1.2510x over previous
//
#include <hip/hip_runtime.h>
#include <cstdint>
#include <cstddef>

#define NB 16
#define NC 64
#define HW 4096
#define SLICE ((size_t)(NB*NC*HW))   // 4194304 floats per state
#define NSTEP 16

// ws layout (float offsets)
#define WS_WT    ((size_t)0)          // wT  [16][3][64 o][64 c] = 196608
#define WS_BV    ((size_t)196608)     // bvec[16][64]            = 1024
#define WS_SV    ((size_t)197632)     // sv  [16][3][64]         = 3072
#define WS_SVMU  ((size_t)200704)     // svmu[16][3][64]         = 3072
#define WS_PLA   ((size_t)203776)     // planes A: 4194304 floats (16 MB)
#define WS_PLB   ((size_t)4398080)    // planes B: 4194304 floats

typedef _Float16 half8 __attribute__((ext_vector_type(8)));  // 8 f16 (4 VGPRs)
typedef float f32x4 __attribute__((ext_vector_type(4)));     // MFMA acc

// wT[b][g][o][c] = (lat @ Wk + bk) at j = o*192 + (g*64+c) ; bvec = lat @ Wb + bb
__global__ __launch_bounds__(256) void k_w(const float* __restrict__ lat,
    const float* __restrict__ Wk, const float* __restrict__ bk,
    const float* __restrict__ Wb, const float* __restrict__ bb,
    float* __restrict__ wT, float* __restrict__ bvec) {
  int t = threadIdx.x;
  if (blockIdx.x < 48) {
    int j = blockIdx.x*256 + t;
    float acc[16];
#pragma unroll
    for (int b = 0; b < 16; b++) acc[b] = 0.f;
#pragma unroll 4
    for (int k = 0; k < 512; k++) {
      float wv = Wk[(size_t)k*12288 + j];
#pragma unroll
      for (int b = 0; b < 16; b++) acc[b] = fmaf(lat[b*512 + k], wv, acc[b]);
    }
    int o = j / 192, cf = j % 192;
    int g = cf >> 6, c = cf & 63;
    float bkj = bk[j];
#pragma unroll
    for (int b = 0; b < 16; b++)
      wT[(((size_t)(b*3 + g))*64 + o)*64 + c] = acc[b] + bkj;
  } else if (t < 64) {
    int j = t;
    float acc[16];
#pragma unroll
    for (int b = 0; b < 16; b++) acc[b] = 0.f;
    for (int k = 0; k < 512; k++) {
      float wv = Wb[k*64 + j];
#pragma unroll
      for (int b = 0; b < 16; b++) acc[b] = fmaf(lat[b*512 + k], wv, acc[b]);
    }
    float bbj = bb[j];
#pragma unroll
    for (int b = 0; b < 16; b++) bvec[b*64 + j] = acc[b] + bbj;
  }
}

// embs slice 0 + initial packed planes (delta at [b][ch0][32][32])
__global__ void k_init(float* __restrict__ e0, float* __restrict__ plA) {
  int f4 = blockIdx.x*256 + threadIdx.x;
  float4 v = make_float4(0.f, 0.f, 0.f, 0.f);
  if (f4 < 1048576) {
    if ((f4 & 65535) == 520) v.x = 1.0f;            // float idx b*262144+2080
    *(float4*)(e0 + (size_t)f4*4) = v;
  } else {
    int g4 = f4 - 1048576;
    if ((g4 & 65535) == 2080)                        // half idx b*524288+16640
      v.x = __uint_as_float(0x00003C00u);            // half pair (1.0h, 0)
    *(float4*)(plA + (size_t)g4*4) = v;
  }
}

// per (b,c): moments of st, gx, gy via separable sobel; float4 column groups.
// thread = (4-col group cg, 4-row band); neighbors via shfl only at group edges.
__global__ __launch_bounds__(256) void k_stats(const float* __restrict__ st,
    float* __restrict__ svb, float* __restrict__ svmub) {
  int c = blockIdx.x, b = blockIdx.y, t = threadIdx.x;
  __shared__ float red[4][6];
  const float* base = st + (size_t)(b*NC + c) * HW;
  int lane = t & 63;
  int cg = t & 15;             // 16 column groups x 4 cols
  int h0 = (t >> 4) * 4;       // 16 bands x 4 rows
  float4 x4[6];
#pragma unroll
  for (int i = 0; i < 6; i++) {
    int row = h0 - 1 + i;
    if (row >= 0 && row < 64) x4[i] = *(const float4*)(base + row*64 + cg*4);
    else                      x4[i] = make_float4(0.f,0.f,0.f,0.f);
  }
  float d[6][4], s[6][4];
#pragma unroll
  for (int i = 0; i < 6; i++) {
    float xm = __shfl(x4[i].w, (lane + 63) & 63);
    float xp = __shfl(x4[i].x, (lane + 1) & 63);
    if (cg == 0)  xm = 0.f;      // col 0 edge (also covers wave-wrap)
    if (cg == 15) xp = 0.f;      // col 63 edge
    d[i][0] = x4[i].y - xm;      s[i][0] = xm + 2.f*x4[i].x + x4[i].y;
    d[i][1] = x4[i].z - x4[i].x; s[i][1] = x4[i].x + 2.f*x4[i].y + x4[i].z;
    d[i][2] = x4[i].w - x4[i].y; s[i][2] = x4[i].y + 2.f*x4[i].z + x4[i].w;
    d[i][3] = xp - x4[i].z;      s[i][3] = x4[i].z + 2.f*x4[i].w + xp;
  }
  float s0=0,q0=0,s1=0,q1=0,s2=0,q2=0;
#pragma unroll
  for (int k = 0; k < 4; k++) {
    float vv[4] = {x4[k+1].x, x4[k+1].y, x4[k+1].z, x4[k+1].w};
#pragma unroll
    for (int j = 0; j < 4; j++) {
      float gx = (d[k][j] + 2.f*d[k+1][j] + d[k+2][j]) * 0.125f;
      float gy = (s[k+2][j] - s[k][j]) * 0.125f;
      s0 += vv[j]; q0 = fmaf(vv[j], vv[j], q0);
      s1 += gx;    q1 = fmaf(gx, gx, q1);
      s2 += gy;    q2 = fmaf(gy, gy, q2);
    }
  }
#pragma unroll
  for (int off = 32; off >= 1; off >>= 1) {
    s0 += __shfl_xor(s0, off); q0 += __shfl_xor(q0, off);
    s1 += __shfl_xor(s1, off); q1 += __shfl_xor(q1, off);
    s2 += __shfl_xor(s2, off); q2 += __shfl_xor(q2, off);
  }
  int wv = t >> 6;
  if (lane == 0) {
    red[wv][0]=s0; red[wv][1]=q0; red[wv][2]=s1;
    red[wv][3]=q1; red[wv][4]=s2; red[wv][5]=q2;
  }
  __syncthreads();
  if (t == 0) {
    float r[6];
#pragma unroll
    for (int u = 0; u < 6; u++) r[u] = red[0][u]+red[1][u]+red[2][u]+red[3][u];
#pragma unroll
    for (int g = 0; g < 3; g++) {
      float mu  = r[2*g] * (1.f/HW);
      float var = fmaxf(r[2*g+1]*(1.f/HW) - mu*mu, 0.f);
      float sv  = 1.f / sqrtf(var + 1e-5f);
      svb  [b*192 + g*64 + c] = sv;
      svmub[b*192 + g*64 + c] = sv * mu;
    }
  }
}

struct SG {
  alignas(16) _Float16 Bwin[32768];   // [pl 2][c8 8][px 256][cj 8] = 64 KB
  float biasL[64];
};  // 64.3 KB -> 2 blocks/CU

// GEMM via pre-packed planes: stage 4-row window (copy), W frags in registers,
// MFMA, sobel-after-mix epilogue, residual via LDS hi+lo reconstruct (no st read),
// pack next-step planes.
__global__ __launch_bounds__(256, 2) void k_gemm(
    float* __restrict__ stn, const float* __restrict__ wT,
    const float* __restrict__ bvec, const float* __restrict__ svb,
    const float* __restrict__ svmub, const _Float16* __restrict__ plR,
    _Float16* __restrict__ plW, const float* __restrict__ leakp,
    float* __restrict__ out0, float* __restrict__ out2, int last) {
  __shared__ SG sh;
  int bid = blockIdx.x, t = threadIdx.x;
  int b = bid >> 5;
  int r0 = ((((bid & 7) << 2) | ((bid >> 3) & 3))) << 1;   // XCD row banding
  int lane = t & 63, wt = t >> 6, c4 = lane >> 4;
  float leak = fminf(fmaxf(leakp[0], 0.001f), 1000.f);

  // ---- stage B window: 4096 16B units, contiguous global -> linear LDS ----
  const _Float16* plb = plR + (size_t)b*524288;
#pragma unroll
  for (int i = 0; i < 16; i++) {
    int u = t + i*256;
    int pl = u >> 11, rest = u & 2047;          // rest = c8*256 + pxl
    int pxg = (r0 - 1)*64 + (rest & 255);
    int pxc = pxg < 0 ? 0 : (pxg > 4095 ? 4095 : pxg);
    const _Float16* gp = plb + ((size_t)pl*8 + (rest >> 8))*32768 + (size_t)pxc*8;
    float4 v = *(const float4*)gp;
    if (pxg < 0 || pxg > 4095) v = make_float4(0.f,0.f,0.f,0.f);
    *(float4*)(sh.Bwin + (size_t)u*8) = v;
  }

  // ---- W fragments (scaled, hi/lo) in registers + bias ----
  int oa = wt*16 + (lane & 15);
  half8 whi[3][2], wlo[3][2];
  float biasacc = 0.f;
#pragma unroll
  for (int g = 0; g < 3; g++) {
#pragma unroll
    for (int kc = 0; kc < 2; kc++) {
      const float* wrow = wT + (((size_t)(b*3 + g))*64 + oa)*64 + kc*32 + c4*8;
      const float* svp  = svb   + b*192 + g*64 + kc*32 + c4*8;
      const float* svmp = svmub + b*192 + g*64 + kc*32 + c4*8;
      float4 wa = *(const float4*)wrow;  float4 wb2 = *(const float4*)(wrow + 4);
      float4 sa = *(const float4*)svp;   float4 sb2 = *(const float4*)(svp + 4);
      float4 ma = *(const float4*)svmp;  float4 mb2 = *(const float4*)(svmp + 4);
      float wv[8] = {wa.x,wa.y,wa.z,wa.w, wb2.x,wb2.y,wb2.z,wb2.w};
      float sv[8] = {sa.x,sa.y,sa.z,sa.w, sb2.x,sb2.y,sb2.z,sb2.w};
      float mv[8] = {ma.x,ma.y,ma.z,ma.w, mb2.x,mb2.y,mb2.z,mb2.w};
      half8 hv, lv;
#pragma unroll
      for (int jj = 0; jj < 8; jj++) {
        float scaled = wv[jj] * sv[jj];
        biasacc = fmaf(wv[jj], mv[jj], biasacc);
        _Float16 h = (_Float16)scaled;
        hv[jj] = h;
        lv[jj] = (_Float16)(scaled - (float)h);
      }
      whi[g][kc] = hv; wlo[g][kc] = lv;
    }
  }
  biasacc += __shfl_xor(biasacc, 16);
  biasacc += __shfl_xor(biasacc, 32);
  if (c4 == 0) sh.biasL[oa] = bvec[b*64 + oa] - biasacc;
  __syncthreads();    // window + bias ready; only barrier in kernel

#pragma unroll
  for (int rr = 0; rr < 2; rr++) {
    int r = r0 + rr;
    f32x4 accA[4] = {}; f32x4 accB[12] = {}; f32x4 accC[12] = {};
#pragma unroll
    for (int kc = 0; kc < 2; kc++) {
#pragma unroll
      for (int n = 0; n < 12; n++) {
        int pxl = rr*64 + n*16 + (lane & 15);
        half8 bh = *(const half8*)(sh.Bwin + ((size_t)(     kc*4 + c4)*256 + pxl)*8);
        half8 bl = *(const half8*)(sh.Bwin + ((size_t)(8 +  kc*4 + c4)*256 + pxl)*8);
        accB[n] = __builtin_amdgcn_mfma_f32_16x16x32_f16(whi[1][kc], bh, accB[n], 0,0,0);
        accB[n] = __builtin_amdgcn_mfma_f32_16x16x32_f16(whi[1][kc], bl, accB[n], 0,0,0);
        accB[n] = __builtin_amdgcn_mfma_f32_16x16x32_f16(wlo[1][kc], bh, accB[n], 0,0,0);
        accC[n] = __builtin_amdgcn_mfma_f32_16x16x32_f16(whi[2][kc], bh, accC[n], 0,0,0);
        accC[n] = __builtin_amdgcn_mfma_f32_16x16x32_f16(whi[2][kc], bl, accC[n], 0,0,0);
        accC[n] = __builtin_amdgcn_mfma_f32_16x16x32_f16(wlo[2][kc], bh, accC[n], 0,0,0);
        if (n >= 4 && n < 8) {
          accA[n-4] = __builtin_amdgcn_mfma_f32_16x16x32_f16(whi[0][kc], bh, accA[n-4], 0,0,0);
          accA[n-4] = __builtin_amdgcn_mfma_f32_16x16x32_f16(whi[0][kc], bl, accA[n-4], 0,0,0);
          accA[n-4] = __builtin_amdgcn_mfma_f32_16x16x32_f16(wlo[0][kc], bh, accA[n-4], 0,0,0);
        }
      }
    }

    // ---- epilogue: sobel on mixed images + bias + residual (st from LDS hi+lo) ----
    float nv16[16];
#pragma unroll
    for (int j = 0; j < 4; j++) {
      int o = wt*16 + (c4 << 2) + j;
      int c8o = o >> 3, cjo = o & 7;
      float Sx[4], Sy[4];
#pragma unroll
      for (int nc = 0; nc < 4; nc++) {
        Sx[nc] = accB[nc][j] + 2.f*accB[4+nc][j] + accB[8+nc][j];
        Sy[nc] = accC[8+nc][j] - accC[nc][j];
      }
      float bt = sh.biasL[o];
#pragma unroll
      for (int nc = 0; nc < 4; nc++) {
        int nm = (nc > 0) ? nc-1 : 0;
        int np = (nc < 3) ? nc+1 : 3;
        float xl1 = __shfl(Sx[nc], (lane - 1) & 63);
        float xl2 = (nc > 0) ? __shfl(Sx[nm], (lane + 15) & 63) : 0.f;
        float xL  = (lane & 15) ? xl1 : xl2;
        float xr1 = __shfl(Sx[nc], (lane + 1) & 63);
        float xr2 = (nc < 3) ? __shfl(Sx[np], (lane - 15) & 63) : 0.f;
        float xR  = ((lane & 15) == 15) ? xr2 : xr1;
        float yl1 = __shfl(Sy[nc], (lane - 1) & 63);
        float yl2 = (nc > 0) ? __shfl(Sy[nm], (lane + 15) & 63) : 0.f;
        float yL  = (lane & 15) ? yl1 : yl2;
        float yr1 = __shfl(Sy[nc], (lane + 1) & 63);
        float yr2 = (nc < 3) ? __shfl(Sy[np], (lane - 15) & 63) : 0.f;
        float yR  = ((lane & 15) == 15) ? yr2 : yr1;
        float gx = (xR - xL) * 0.125f;
        float gy = (yL + 2.f*Sy[nc] + yR) * 0.125f;
        float nw = accA[nc][j] + gx + gy + bt;
        int wpxc = nc*16 + (lane & 15);
        int wpx = (1 + rr)*64 + wpxc;        // window row of r
        float sthi = (float)sh.Bwin[((size_t)c8o*256 + wpx)*8 + cjo];
        float stlo = (float)sh.Bwin[((size_t)(8 + c8o)*256 + wpx)*8 + cjo];
        float nvv = sthi + stlo + leak * nw;
        size_t gi = (size_t)(b*NC + o)*HW + (size_t)r*64 + wpxc;
        stn[gi] = nvv;
        nv16[j*4 + nc] = nvv;
        if (last && o < 3) {
          size_t oi = (size_t)(b*3 + o)*HW + (size_t)r*64 + wpxc;
          out2[oi] = nvv;
          out0[oi] = fminf(fmaxf(nvv, -1.f), 1.f);
        }
      }
    }

    // ---- pack nv -> next-step planes (skip on last step) ----
    if (!last) {
      int pl = c4 & 1;                 // 0 = hi plane, 1 = lo plane
      int g8 = wt*2 + (c4 >> 1);       // 8-channel group
      _Float16* pw = plW + (size_t)b*524288 + ((size_t)pl*8 + g8)*32768;
#pragma unroll
      for (int nc = 0; nc < 4; nc++) {
        float own[4], rcv[4];
#pragma unroll
        for (int j = 0; j < 4; j++) {
          own[j] = nv16[j*4 + nc];
          rcv[j] = __shfl_xor(own[j], 16);
        }
        float xx[8];
#pragma unroll
        for (int jj = 0; jj < 8; jj++)
          xx[jj] = ((jj >> 2) == (c4 & 1)) ? own[jj & 3] : rcv[jj & 3];
        half8 v8;
        if (pl == 0) {
#pragma unroll
          for (int jj = 0; jj < 8; jj++) v8[jj] = (_Float16)xx[jj];
        } else {
#pragma unroll
          for (int jj = 0; jj < 8; jj++) {
            _Float16 h = (_Float16)xx[jj];
            v8[jj] = (_Float16)(xx[jj] - (float)h);
          }
        }
        int gpx = r*64 + nc*16 + (lane & 15);
        *(half8*)(pw + (size_t)gpx*8) = v8;
      }
    }
  }
}

extern "C" void kernel_launch(void* const* d_in, const int* in_sizes, int n_in,
                              void* d_out, int out_size, void* d_ws, size_t ws_size,
                              hipStream_t stream) {
  const float* lat   = (const float*)d_in[0];
  const float* Wk    = (const float*)d_in[1];
  const float* bk    = (const float*)d_in[2];
  const float* Wb    = (const float*)d_in[3];
  const float* bb    = (const float*)d_in[4];
  const float* leakp = (const float*)d_in[5];
  float* out = (float*)d_out;
  float* ws  = (float*)d_ws;
  float* wT    = ws + WS_WT;
  float* bvec  = ws + WS_BV;
  float* svbuf = ws + WS_SV;
  float* svmub = ws + WS_SVMU;
  _Float16* plbuf[2] = { (_Float16*)(ws + WS_PLA), (_Float16*)(ws + WS_PLB) };
  float* out0 = out;
  float* embs = out + 196608;
  float* out2 = out + 196608 + 17*SLICE;

  hipLaunchKernelGGL(k_w,    dim3(49),   dim3(256), 0, stream, lat, Wk, bk, Wb, bb, wT, bvec);
  hipLaunchKernelGGL(k_init, dim3(8192), dim3(256), 0, stream, embs, ws + WS_PLA);
  for (int tstep = 0; tstep < NSTEP; tstep++) {
    const float* stc = embs + (size_t)tstep*SLICE;
    float*       stn = embs + (size_t)(tstep+1)*SLICE;
    hipLaunchKernelGGL(k_stats, dim3(64,16), dim3(256), 0, stream, stc, svbuf, svmub);
    hipLaunchKernelGGL(k_gemm, dim3(512), dim3(256), 0, stream,
                       stn, wT, bvec, svbuf, svmub,
                       plbuf[tstep & 1], plbuf[(tstep+1) & 1], leakp,
                       out0, out2, (int)(tstep == NSTEP-1));
  }
}